// Round 2
// baseline (212.012 us; speedup 1.0000x reference)
//
#include <hip/hip_runtime.h>
#include <hip/hip_bf16.h>

#define NN 4096
#define DD 256
#define OO 256

typedef __attribute__((ext_vector_type(4))) float f32x4;
typedef __attribute__((ext_vector_type(8))) short bf16x8;
typedef __attribute__((ext_vector_type(4))) unsigned int u32x4;

__device__ __forceinline__ short f2bfs(float f) {
    __hip_bfloat16 h = __float2bfloat16(f);
    short s;
    __builtin_memcpy(&s, &h, 2);
    return s;
}

// K1: XWT[o][m] = sum_k X[m][k] * W[k][o], output bf16, layout [OO][NN] row-major.
__global__ __launch_bounds__(256) void k1_xwt(
    const float* __restrict__ X, const float* __restrict__ W,
    unsigned short* __restrict__ XWT)
{
    __shared__ float xs[16][DD];
    const int t = threadIdx.x;
    const int m0 = blockIdx.x * 16;

    #pragma unroll
    for (int i = 0; i < 16; ++i)
        xs[i][t] = X[(size_t)(m0 + i) * DD + t];
    __syncthreads();

    float acc[16];
    #pragma unroll
    for (int m = 0; m < 16; ++m) acc[m] = 0.f;

    for (int k0 = 0; k0 < DD; k0 += 4) {
        float w0 = W[(size_t)(k0 + 0) * OO + t];
        float w1 = W[(size_t)(k0 + 1) * OO + t];
        float w2 = W[(size_t)(k0 + 2) * OO + t];
        float w3 = W[(size_t)(k0 + 3) * OO + t];
        #pragma unroll
        for (int m = 0; m < 16; ++m) {
            const f32x4 xv = *reinterpret_cast<const f32x4*>(&xs[m][k0]);
            acc[m] = fmaf(xv[0], w0, acc[m]);
            acc[m] = fmaf(xv[1], w1, acc[m]);
            acc[m] = fmaf(xv[2], w2, acc[m]);
            acc[m] = fmaf(xv[3], w3, acc[m]);
        }
    }

    unsigned int p[8];
    #pragma unroll
    for (int i = 0; i < 8; ++i) {
        unsigned lo = (unsigned short)f2bfs(acc[2 * i]);
        unsigned hi = (unsigned short)f2bfs(acc[2 * i + 1]);
        p[i] = lo | (hi << 16);
    }
    u32x4* dst = reinterpret_cast<u32x4*>(XWT + (size_t)t * NN + m0);
    dst[0] = (u32x4){p[0], p[1], p[2], p[3]};
    dst[1] = (u32x4){p[4], p[5], p[6], p[7]};
}

// K2: fused partial over n-chunk:
//   gemm_part[chunk][y,o] = sum_{n in chunk} Beta[n,y]*XW[n,o]
//   adj_part[chunk][y,c]  = sum_{n in chunk} Beta[n,y]*adj[n,y,c]
// grid (256 y-tiles, nchunk), 512 threads = 8 waves; wave w owns o in [32w, 32w+32).
// If nchunk == 1, applies the full epilogue directly to Out.
__global__ __launch_bounds__(512) void k2_fused(
    const float* __restrict__ Beta, const unsigned short* __restrict__ XWT,
    const float* __restrict__ Adj, const float* __restrict__ W,
    const float* __restrict__ bias, float* __restrict__ Out,
    float* __restrict__ gpart, float* __restrict__ apart,
    int nchunk, int clen)
{
    const int t = threadIdx.x;
    const int lane = t & 63;
    const int wave = t >> 6;      // 0..7
    const int g16 = lane >> 4;    // 0..3
    const int r16 = lane & 15;
    const int tile = blockIdx.x;
    const int chunk = blockIdx.y;
    const int y0 = tile * 16;
    const int nbase = chunk * clen;

    // GEMM pointers: A = Beta^T fragment, B = XWT rows
    const float* bA = Beta + (size_t)(nbase + 8 * g16) * NN + (y0 + r16);
    const unsigned short* xw0 = XWT + (size_t)(32 * wave + r16) * NN + nbase + 8 * g16;
    const unsigned short* xw1 = xw0 + (size_t)16 * NN;

    // adjacency: thread handles (y = t&15, n-offset g = t>>4) within each 32-n step
    const int ga = t >> 4;        // 0..31
    const int ya = t & 15;
    const float* bS = Beta + (size_t)(nbase + ga) * NN + (y0 + ya);
    const float* aS = Adj + ((size_t)(nbase + ga) * NN + (y0 + ya)) * 3;

    f32x4 d0 = {0.f, 0.f, 0.f, 0.f};
    f32x4 d1 = {0.f, 0.f, 0.f, 0.f};
    float agg0 = 0.f, agg1 = 0.f, agg2 = 0.f;

    for (int n0 = 0; n0 < clen; n0 += 32) {
        float a0 = bA[0 * NN];
        float a1 = bA[1 * NN];
        float a2 = bA[2 * NN];
        float a3 = bA[3 * NN];
        float a4 = bA[4 * NN];
        float a5 = bA[5 * NN];
        float a6 = bA[6 * NN];
        float a7 = bA[7 * NN];
        bf16x8 av;
        av[0] = f2bfs(a0); av[1] = f2bfs(a1); av[2] = f2bfs(a2); av[3] = f2bfs(a3);
        av[4] = f2bfs(a4); av[5] = f2bfs(a5); av[6] = f2bfs(a6); av[7] = f2bfs(a7);

        bf16x8 b0 = *reinterpret_cast<const bf16x8*>(xw0);
        bf16x8 b1 = *reinterpret_cast<const bf16x8*>(xw1);

        d0 = __builtin_amdgcn_mfma_f32_16x16x32_bf16(av, b0, d0, 0, 0, 0);
        d1 = __builtin_amdgcn_mfma_f32_16x16x32_bf16(av, b1, d1, 0, 0, 0);

        float bv = *bS;
        agg0 = fmaf(bv, aS[0], agg0);
        agg1 = fmaf(bv, aS[1], agg1);
        agg2 = fmaf(bv, aS[2], agg2);

        bA += (size_t)32 * NN;
        xw0 += 32;
        xw1 += 32;
        bS += (size_t)32 * NN;
        aS += (size_t)32 * NN * 3;
    }

    // reduce agg over the 32 n-groups
    __shared__ float lagg[32][16][3];
    __shared__ float fin[16][3];
    lagg[ga][ya][0] = agg0;
    lagg[ga][ya][1] = agg1;
    lagg[ga][ya][2] = agg2;
    __syncthreads();
    if (t < 48) {
        const int yy = t / 3, cc = t % 3;
        float s = 0.f;
        #pragma unroll
        for (int g = 0; g < 32; ++g) s += lagg[g][yy][cc];
        fin[yy][cc] = s;
    }
    __syncthreads();

    if (nchunk == 1) {
        // full epilogue: out = D + agg @ Wa + bias
        #pragma unroll
        for (int f = 0; f < 2; ++f) {
            const int o = 32 * wave + 16 * f + r16;
            const float wa0 = W[(size_t)(DD + 0) * OO + o];
            const float wa1 = W[(size_t)(DD + 1) * OO + o];
            const float wa2 = W[(size_t)(DD + 2) * OO + o];
            const float bo  = bias[o];
            const f32x4 dd = f ? d1 : d0;
            #pragma unroll
            for (int r = 0; r < 4; ++r) {
                const int yl = 4 * g16 + r;
                const float add = fin[yl][0] * wa0 + fin[yl][1] * wa1 + fin[yl][2] * wa2 + bo;
                Out[(size_t)(y0 + yl) * OO + o] = dd[r] + add;
            }
        }
    } else {
        // partial writes
        if (t < 48)
            apart[((size_t)chunk * 256 + tile) * 48 + t] = fin[t / 3][t % 3];
        float* gp = gpart + ((size_t)chunk * NN + y0) * OO;
        #pragma unroll
        for (int f = 0; f < 2; ++f) {
            const int o = 32 * wave + 16 * f + r16;
            const f32x4 dd = f ? d1 : d0;
            #pragma unroll
            for (int r = 0; r < 4; ++r) {
                const int yl = 4 * g16 + r;
                gp[(size_t)yl * OO + o] = dd[r];
            }
        }
    }
}

// K3: out[y,o] = sum_ch gpart + (sum_ch apart[y]) @ Wa + bias
__global__ __launch_bounds__(256) void k3_reduce(
    const float* __restrict__ gpart, const float* __restrict__ apart,
    const float* __restrict__ W, const float* __restrict__ bias,
    float* __restrict__ Out, int nchunk)
{
    const int idx = blockIdx.x * 256 + threadIdx.x;   // 0 .. NN*OO/4-1
    const int o = (idx << 2) & (OO - 1);
    const int y = idx >> 6;                            // (idx*4)/OO

    f32x4 acc = {0.f, 0.f, 0.f, 0.f};
    for (int ch = 0; ch < nchunk; ++ch) {
        const f32x4 g = *reinterpret_cast<const f32x4*>(
            &gpart[((size_t)ch * NN + y) * OO + o]);
        acc[0] += g[0]; acc[1] += g[1]; acc[2] += g[2]; acc[3] += g[3];
    }

    float a0 = 0.f, a1 = 0.f, a2 = 0.f;
    const int tile = y >> 4, yl = y & 15;
    for (int ch = 0; ch < nchunk; ++ch) {
        const float* ap = apart + ((size_t)ch * 256 + tile) * 48 + yl * 3;
        a0 += ap[0]; a1 += ap[1]; a2 += ap[2];
    }

    #pragma unroll
    for (int j = 0; j < 4; ++j) {
        const int oo = o + j;
        Out[(size_t)y * OO + oo] = acc[j]
            + a0 * W[(size_t)(DD + 0) * OO + oo]
            + a1 * W[(size_t)(DD + 1) * OO + oo]
            + a2 * W[(size_t)(DD + 2) * OO + oo]
            + bias[oo];
    }
}

extern "C" void kernel_launch(void* const* d_in, const int* in_sizes, int n_in,
                              void* d_out, int out_size, void* d_ws, size_t ws_size,
                              hipStream_t stream) {
    (void)in_sizes; (void)n_in; (void)out_size;
    const float* adj  = (const float*)d_in[0];  // (N, N, C)
    const float* X    = (const float*)d_in[1];  // (N, D)
    const float* Beta = (const float*)d_in[2];  // (N, N)
    const float* W    = (const float*)d_in[3];  // (D+C, O)
    const float* bias = (const float*)d_in[4];  // (O)
    float* out = (float*)d_out;                 // (N, O) fp32

    unsigned short* XWT = (unsigned short*)d_ws;       // bf16 [OO][NN], 2 MB
    const size_t xwt_bytes = (size_t)OO * NN * 2;

    // choose n-split from available scratch (deterministic: ws_size is fixed)
    const size_t per_chunk = (size_t)NN * OO * 4 + 256 * 48 * 4;
    int nchunk = 1;
    if (ws_size >= xwt_bytes + 4 * per_chunk) nchunk = 4;
    else if (ws_size >= xwt_bytes + 2 * per_chunk) nchunk = 2;
    const int clen = NN / nchunk;

    float* gpart = (float*)((char*)d_ws + xwt_bytes);
    float* apart = (float*)((char*)d_ws + xwt_bytes + (size_t)nchunk * NN * OO * 4);

    k1_xwt<<<dim3(NN / 16), dim3(256), 0, stream>>>(X, W, XWT);
    k2_fused<<<dim3(NN / 16, nchunk), dim3(512), 0, stream>>>(
        Beta, XWT, adj, W, bias, out, gpart, apart, nchunk, clen);
    if (nchunk > 1)
        k3_reduce<<<dim3(NN * OO / 4 / 256), dim3(256), 0, stream>>>(
            gpart, apart, W, bias, out, nchunk);
}

// Round 3
// 132.643 us; speedup vs baseline: 1.5984x; 1.5984x over previous
//
#include <hip/hip_runtime.h>
#include <hip/hip_bf16.h>

#define NN 4096
#define DD 256
#define OO 256
#define YT 64
#define NSTEP 32

typedef __attribute__((ext_vector_type(4))) float f32x4;
typedef __attribute__((ext_vector_type(8))) short bf16x8;
typedef __attribute__((ext_vector_type(4))) unsigned int u32x4;

__device__ __forceinline__ short f2bfs(float f) {
    __hip_bfloat16 h = __float2bfloat16(f);
    short s;
    __builtin_memcpy(&s, &h, 2);
    return s;
}

// direct global->LDS 16B copy; LDS dest must be linear-in-lane (it is: dest = base + 4*slot floats)
__device__ __forceinline__ void gl_lds16(const float* gsrc, float* ldst) {
    __builtin_amdgcn_global_load_lds(
        (const __attribute__((address_space(1))) void*)gsrc,
        (__attribute__((address_space(3))) void*)ldst,
        16, 0, 0);
}

// K1: XWT[o][m] = sum_k X[m][k] * W[k][o], output bf16, layout [OO][NN] row-major.
__global__ __launch_bounds__(256) void k1_xwt(
    const float* __restrict__ X, const float* __restrict__ W,
    unsigned short* __restrict__ XWT)
{
    __shared__ float xs[16][DD];
    const int t = threadIdx.x;
    const int m0 = blockIdx.x * 16;

    #pragma unroll
    for (int i = 0; i < 16; ++i)
        xs[i][t] = X[(size_t)(m0 + i) * DD + t];
    __syncthreads();

    float acc[16];
    #pragma unroll
    for (int m = 0; m < 16; ++m) acc[m] = 0.f;

    for (int k0 = 0; k0 < DD; k0 += 4) {
        float w0 = W[(size_t)(k0 + 0) * OO + t];
        float w1 = W[(size_t)(k0 + 1) * OO + t];
        float w2 = W[(size_t)(k0 + 2) * OO + t];
        float w3 = W[(size_t)(k0 + 3) * OO + t];
        #pragma unroll
        for (int m = 0; m < 16; ++m) {
            const f32x4 xv = *reinterpret_cast<const f32x4*>(&xs[m][k0]);
            acc[m] = fmaf(xv[0], w0, acc[m]);
            acc[m] = fmaf(xv[1], w1, acc[m]);
            acc[m] = fmaf(xv[2], w2, acc[m]);
            acc[m] = fmaf(xv[3], w3, acc[m]);
        }
    }

    unsigned int p[8];
    #pragma unroll
    for (int i = 0; i < 8; ++i) {
        unsigned lo = (unsigned short)f2bfs(acc[2 * i]);
        unsigned hi = (unsigned short)f2bfs(acc[2 * i + 1]);
        p[i] = lo | (hi << 16);
    }
    u32x4* dst = reinterpret_cast<u32x4*>(XWT + (size_t)t * NN + m0);
    dst[0] = (u32x4){p[0], p[1], p[2], p[3]};
    dst[1] = (u32x4){p[4], p[5], p[6], p[7]};
}

// K2: per (y-tile of 64, n-chunk): LDS-staged streaming of Beta + adjacency.
//   gpart[chunk][y][o] = sum_{n in chunk} Beta[n,y]*XW[n,o]        (bf16 MFMA)
//   apart[chunk][tile][y][c] = sum_{n in chunk} Beta[n,y]*adj[n,y,c] (f32)
// 512 threads = 8 waves; wave w: wo=w&1 (o-strip 128), wy=w>>1 (y-strip 16).
__global__ __launch_bounds__(512, 4) void k2_fused(
    const float* __restrict__ Beta, const unsigned short* __restrict__ XWT,
    const float* __restrict__ Adj,
    float* __restrict__ gpart, float* __restrict__ apart,
    int clen)
{
    __shared__ float adj_s[2][NSTEP][YT * 3];   // 48 KB
    __shared__ float beta_s[2][NSTEP][YT];      // 16 KB
    __shared__ float lagg[8][YT][3];            // 6 KB

    const int t = threadIdx.x;
    const int lane = t & 63;
    const int w = t >> 6;          // wave 0..7
    const int wo = w & 1;
    const int wy = w >> 1;
    const int g16 = lane >> 4;
    const int r16 = lane & 15;
    const int tile = blockIdx.x;
    const int chunk = blockIdx.y;
    const int y0 = tile * YT;
    const int nbase = chunk * clen;
    const int nsteps = clen / NSTEP;

    // --- staging: fully dense 16B/lane global->LDS, linear LDS layout ---
    const int br = t >> 4, boff = (t & 15) * 4;            // beta: 512 slots
    const int s1 = 512 + t, s2 = 1024 + t;                 // adj: 1536 slots
    const int ar0 = t / 48,  ao0 = (t % 48) * 4;
    const int ar1 = s1 / 48, ao1 = (s1 % 48) * 4;
    const int ar2 = s2 / 48, ao2 = (s2 % 48) * 4;

    #define STAGE(b, gn)                                                            \
        do {                                                                        \
            gl_lds16(Beta + (size_t)((gn) + br) * NN + y0 + boff,                   \
                     &beta_s[b][br][boff]);                                         \
            gl_lds16(Adj + ((size_t)((gn) + ar0) * NN + y0) * 3 + ao0,              \
                     &adj_s[b][ar0][ao0]);                                          \
            gl_lds16(Adj + ((size_t)((gn) + ar1) * NN + y0) * 3 + ao1,              \
                     &adj_s[b][ar1][ao1]);                                          \
            gl_lds16(Adj + ((size_t)((gn) + ar2) * NN + y0) * 3 + ao2,              \
                     &adj_s[b][ar2][ao2]);                                          \
        } while (0)

    STAGE(0, nbase);

    f32x4 acc[8];
    #pragma unroll
    for (int i = 0; i < 8; ++i) acc[i] = (f32x4){0.f, 0.f, 0.f, 0.f};
    float ag0 = 0.f, ag1 = 0.f, ag2 = 0.f;

    const unsigned short* xwbase = XWT + (size_t)(128 * wo + r16) * NN + nbase + 8 * g16;

    __syncthreads();   // drains vmcnt(0): buffer 0 staged

    for (int st = 0; st < nsteps; ++st) {
        const int cur = st & 1;

        // B-frags from XWT (L2-hot) -- issue first so stage loads queue behind
        bf16x8 bf[8];
        const unsigned short* xp = xwbase + (size_t)st * NSTEP;
        #pragma unroll
        for (int of = 0; of < 8; ++of)
            bf[of] = *reinterpret_cast<const bf16x8*>(xp + (size_t)of * 16 * NN);

        // prefetch next tile into the other buffer (latency hides under compute)
        if (st + 1 < nsteps) {
            const int gn = nbase + (st + 1) * NSTEP;
            STAGE(cur ^ 1, gn);
        }

        // A-frag: Beta rows = k, col = y (convention verified in round 1)
        bf16x8 av;
        #pragma unroll
        for (int j = 0; j < 8; ++j)
            av[j] = f2bfs(beta_s[cur][8 * g16 + j][16 * wy + r16]);

        #pragma unroll
        for (int of = 0; of < 8; ++of)
            acc[of] = __builtin_amdgcn_mfma_f32_16x16x32_bf16(av, bf[of], acc[of], 0, 0, 0);

        // adjacency partial: wave w owns n = 4w..4w+3, lane = y
        #pragma unroll
        for (int i = 0; i < 4; ++i) {
            const int n = 4 * w + i;
            const float bv = beta_s[cur][n][lane];
            ag0 = fmaf(bv, adj_s[cur][n][lane * 3 + 0], ag0);
            ag1 = fmaf(bv, adj_s[cur][n][lane * 3 + 1], ag1);
            ag2 = fmaf(bv, adj_s[cur][n][lane * 3 + 2], ag2);
        }

        __syncthreads();   // next buffer staged (vmcnt drain) + all waves done with cur
    }

    // reduce agg over the 8 waves
    lagg[w][lane][0] = ag0;
    lagg[w][lane][1] = ag1;
    lagg[w][lane][2] = ag2;
    __syncthreads();
    if (t < YT * 3) {
        const int yy = t / 3, cc = t % 3;
        float s = 0.f;
        #pragma unroll
        for (int g = 0; g < 8; ++g) s += lagg[g][yy][cc];
        apart[((size_t)chunk * (NN / YT) + tile) * (YT * 3) + t] = s;
    }

    // GEMM partial write (coalesced 64B per 16 lanes)
    float* gp = gpart + ((size_t)chunk * NN + y0) * OO;
    #pragma unroll
    for (int of = 0; of < 8; ++of) {
        const int o = 128 * wo + 16 * of + r16;
        #pragma unroll
        for (int r = 0; r < 4; ++r) {
            const int yl = 16 * wy + 4 * g16 + r;
            gp[(size_t)yl * OO + o] = acc[of][r];
        }
    }
    #undef STAGE
}

// K3: out[y,o] = sum_ch gpart + (sum_ch apart[y]) @ Wa + bias
__global__ __launch_bounds__(256) void k3_reduce(
    const float* __restrict__ gpart, const float* __restrict__ apart,
    const float* __restrict__ W, const float* __restrict__ bias,
    float* __restrict__ Out, int nchunk)
{
    const int idx = blockIdx.x * 256 + threadIdx.x;   // 0 .. NN*OO/4-1
    const int o = (idx << 2) & (OO - 1);
    const int y = idx >> 6;

    f32x4 acc = {0.f, 0.f, 0.f, 0.f};
    for (int ch = 0; ch < nchunk; ++ch) {
        const f32x4 g = *reinterpret_cast<const f32x4*>(
            &gpart[((size_t)ch * NN + y) * OO + o]);
        acc[0] += g[0]; acc[1] += g[1]; acc[2] += g[2]; acc[3] += g[3];
    }

    float a0 = 0.f, a1 = 0.f, a2 = 0.f;
    const int tile = y >> 6, yl = y & 63;
    for (int ch = 0; ch < nchunk; ++ch) {
        const float* ap = apart + ((size_t)ch * (NN / YT) + tile) * (YT * 3) + yl * 3;
        a0 += ap[0]; a1 += ap[1]; a2 += ap[2];
    }

    #pragma unroll
    for (int j = 0; j < 4; ++j) {
        const int oo = o + j;
        Out[(size_t)y * OO + oo] = acc[j]
            + a0 * W[(size_t)(DD + 0) * OO + oo]
            + a1 * W[(size_t)(DD + 1) * OO + oo]
            + a2 * W[(size_t)(DD + 2) * OO + oo]
            + bias[oo];
    }
}

extern "C" void kernel_launch(void* const* d_in, const int* in_sizes, int n_in,
                              void* d_out, int out_size, void* d_ws, size_t ws_size,
                              hipStream_t stream) {
    (void)in_sizes; (void)n_in; (void)out_size;
    const float* adj  = (const float*)d_in[0];  // (N, N, C)
    const float* X    = (const float*)d_in[1];  // (N, D)
    const float* Beta = (const float*)d_in[2];  // (N, N)
    const float* W    = (const float*)d_in[3];  // (D+C, O)
    const float* bias = (const float*)d_in[4];  // (O)
    float* out = (float*)d_out;                 // (N, O) fp32

    unsigned short* XWT = (unsigned short*)d_ws;       // bf16 [OO][NN], 2 MB
    const size_t xwt_bytes = (size_t)OO * NN * 2;

    const size_t per_chunk = (size_t)NN * OO * 4 + (size_t)(NN / YT) * YT * 3 * 4;
    int nchunk = 4;
    if (ws_size >= xwt_bytes + 8 * per_chunk) nchunk = 8;
    const int clen = NN / nchunk;

    float* gpart = (float*)((char*)d_ws + xwt_bytes);
    float* apart = (float*)((char*)d_ws + xwt_bytes + (size_t)nchunk * NN * OO * 4);

    k1_xwt<<<dim3(NN / 16), dim3(256), 0, stream>>>(X, W, XWT);
    k2_fused<<<dim3(NN / YT, nchunk), dim3(512), 0, stream>>>(
        Beta, XWT, adj, gpart, apart, clen);
    k3_reduce<<<dim3(NN * OO / 4 / 256), dim3(256), 0, stream>>>(
        gpart, apart, W, bias, out, nchunk);
}